// Round 24
// baseline (196.147 us; speedup 1.0000x reference)
//
#include <hip/hip_runtime.h>
#include <hip/hip_bf16.h>
#include <math.h>

#define NH_ 4
#define S_  49
#define B_  16
#define H_  112
#define W_  112
#define WT  16

typedef __attribute__((ext_vector_type(8))) short short8;
typedef __attribute__((ext_vector_type(4))) float f32x4;

__device__ __forceinline__ unsigned short f2bf(float f) {
  union { __hip_bfloat16 h; unsigned short u; } c;
  c.h = __float2bfloat16(f);
  return c.u;
}
__device__ __forceinline__ short8 cvt8(float4 a, float4 b) {
  union { short8 s; unsigned short u[8]; } r;
  r.u[0] = f2bf(a.x); r.u[1] = f2bf(a.y); r.u[2] = f2bf(a.z); r.u[3] = f2bf(a.w);
  r.u[4] = f2bf(b.x); r.u[5] = f2bf(b.y); r.u[6] = f2bf(b.z); r.u[7] = f2bf(b.w);
  return r.s;
}

// ---- prep: Wqk f32 [256][128] -> bf16, HEAD-GROUPED row order:
//   Wb'[n'] = Wqk[orig], n' = h*64 + c, orig = 8*(c>>1) + 2h + (c&1).
__global__ void wprep(const float* __restrict__ Wqk, unsigned short* __restrict__ Wb) {
  int oi = (blockIdx.x * 256 + threadIdx.x) * 4;   // output element index
  int np = oi >> 7;          // n' = 0..255
  int k  = oi & 127;
  int h = np >> 6, c = np & 63;
  int orig = 8 * (c >> 1) + 2 * h + (c & 1);
  float4 w = *(const float4*)(Wqk + orig * 128 + k);
  ushort4 o; o.x = f2bf(w.x); o.y = f2bf(w.y); o.z = f2bf(w.z); o.w = f2bf(w.w);
  *(ushort4*)(Wb + oi) = o;
}

// LDS map (bytes) — Vt moved to REGISTERS:
//   0     : qk planes, 8 x 4112 = 32896 (plane = head*2+s; [64 rows][32 e] bf16, 16B skew)
//           outb f32 [49][132] = 25872 aliases after barrier #1 (last plane reads = QK)
//   32896 : posl f32 [169] = 676      -> total 33572 -> 4 blocks/CU
#define PSTR   4112
#define SM_POS 32896
#define SM_TOT 33572

__global__ __launch_bounds__(256, 4) void swin_fused(
    const float* __restrict__ x, const float* __restrict__ v,
    const float* __restrict__ bqk, const float* __restrict__ pos,
    const unsigned short* __restrict__ Wb, float* __restrict__ out)
{
  __shared__ __align__(16) char smem[SM_TOT];
  float* posl = (float*)(smem + SM_POS);

  const int tid  = threadIdx.x;
  const int lane = tid & 63;
  const int g    = lane >> 4, l15 = lane & 15;
  const int wv   = tid >> 6;
  const int blk  = blockIdx.x;
  const int ww   = blk % WT, wh = (blk / WT) % WT, b = blk / (WT * WT);

  if (tid < 169) posl[tid] = pos[tid];

  // ---- up-front loads: 4 biases (own head)
  float bq[4];
  #pragma unroll
  for (int q = 0; q < 4; ++q)
    bq[q] = bqk[64 * q + 8 * (l15 >> 1) + 2 * wv + (l15 & 1)];

  // ---- V fragments in REGISTERS (replaces LDS Vt).
  //   vfr[et][ks].h[j] = bf16(V[t][c = 4*(16et+l15)+wv]),
  //   t = 32ks + 16*(j>>2) + 4g + (j&3); t>=49 -> 0. Verified == r22 Vt layout.
  short8 vfr[2][2];
  {
    int voff[16]; bool vok[16];
    #pragma unroll
    for (int u = 0; u < 4; ++u)
      #pragma unroll
      for (int jr = 0; jr < 4; ++jr) {
        const int t = 16 * u + 4 * g + jr;
        const bool ok = (t < S_);
        const int tc = ok ? t : 0;
        const int px = tc / 7, py = tc - 7 * px;
        const int gi = (wh * 7 + px + 4) % H_;
        const int gj = (ww * 7 + py + 4) % W_;
        voff[u * 4 + jr] = (gi * W_ + gj) * 128 + 4 * l15 + wv;
        vok[u * 4 + jr] = ok;
      }
    const float* vb_ = v + (size_t)b * H_ * W_ * 128;
    #pragma unroll
    for (int et = 0; et < 2; ++et)
      #pragma unroll
      for (int ks = 0; ks < 2; ++ks) {
        union { short8 s8; unsigned short h[8]; } pku;
        #pragma unroll
        for (int j = 0; j < 8; ++j) {
          const int i16 = (2 * ks + (j >> 2)) * 4 + (j & 3);
          float val = vok[i16] ? vb_[voff[i16] + et * 64] : 0.f;
          pku.h[j] = f2bf(val);
        }
        vfr[et][ks] = pku.s8;
      }
  }

  // ---- A-fragments for ALL 4 m-tiles (wave owns whole window for its head)
  short8 af[4][4];
  #pragma unroll
  for (int mt = 0; mt < 4; ++mt) {
    const int prow = 16 * mt + l15;
    const int pc = prow < S_ ? prow : S_ - 1;   // clamp; rows >=49 discarded later
    const int px = pc / 7, py = pc % 7;
    const int gi = (wh * 7 + px + 4) % H_;
    const int gj = (ww * 7 + py + 4) % W_;
    const float* xrow = x + (((size_t)b * H_ + gi) * W_ + gj) * 128;
    #pragma unroll
    for (int kk = 0; kk < 4; ++kk) {
      float4 a0 = *(const float4*)(xrow + kk * 32 + g * 8);
      float4 a1 = *(const float4*)(xrow + kk * 32 + g * 8 + 4);
      af[mt][kk] = cvt8(a0, a1);
    }
  }

  // ---- projection, head-local: wave wv computes all 64 rows x its head's 64
  //      channels (Wb' rows wv*64 .. wv*64+63). Writes ONLY its own planes ->
  //      QK^T below needs no cross-wave barrier.
  {
    char* plane0 = smem + (wv * 2) * PSTR;
    #pragma unroll
    for (int q = 0; q < 4; ++q) {
      const int nb = (wv * 64 + q * 16 + l15) * 128;
      short8 bfr[4];
      #pragma unroll
      for (int kk = 0; kk < 4; ++kk)
        bfr[kk] = *(const short8*)(Wb + nb + kk * 32 + g * 8);
      const float bias = bq[q];
      char* plane = plane0 + (l15 & 1) * PSTR;             // s = l15&1
      const int eoff = (q * 8 + (l15 >> 1)) * 2;           // e = 8q + (l15>>1)
      #pragma unroll
      for (int mt = 0; mt < 4; ++mt) {
        f32x4 acc = {0.f, 0.f, 0.f, 0.f};
        #pragma unroll
        for (int kk = 0; kk < 4; ++kk)
          acc = __builtin_amdgcn_mfma_f32_16x16x32_bf16(af[mt][kk], bfr[kk], acc, 0, 0, 0);
        const int mbase = 16 * mt + 4 * g;
        #pragma unroll
        for (int r = 0; r < 4; ++r)
          *(unsigned short*)(plane + (mbase + r) * 64 + eoff) = f2bf(acc[r] + bias);
      }
    }
  }
  // (no barrier: planes of head wv are wave-private; lgkmcnt orders RAW below)

  // ---- attention: wave = head; SWAPPED QK^T -> lane-local P columns
  const bool maskR = (wh == WT - 1), maskC = (ww == WT - 1);
  const char* qpl = smem + (wv * 2 + 0) * PSTR;
  const char* kpl = smem + (wv * 2 + 1) * PSTR;
  short8 qf[4], kf[4];
  #pragma unroll
  for (int t4 = 0; t4 < 4; ++t4) {
    qf[t4] = *(const short8*)(qpl + (16 * t4 + l15) * 64 + g * 16);
    kf[t4] = *(const short8*)(kpl + (16 * t4 + l15) * 64 + g * 16);
  }

  // st[nt][mt]: D[row = t = 16nt+4g+r][col = m = 16mt+l15]
  f32x4 st[4][4];
  #pragma unroll
  for (int nt = 0; nt < 4; ++nt)
    #pragma unroll
    for (int mt = 0; mt < 4; ++mt) {
      f32x4 z = {0.f, 0.f, 0.f, 0.f};
      st[nt][mt] = __builtin_amdgcn_mfma_f32_16x16x32_bf16(kf[nt], qf[mt], z, 0, 0, 0);
    }

  // ---- t-geometry + shift masks BEFORE the barrier (lane-local, no posl dep)
  int tix[4][4]; bool txg[4][4], tyg[4][4], tvl[4][4];
  #pragma unroll
  for (int nt = 0; nt < 4; ++nt)
    #pragma unroll
    for (int r = 0; r < 4; ++r) {
      const int t = 16 * nt + 4 * g + r;
      const int tx = t / 7, ty = t - 7 * tx;
      tix[nt][r] = tx * 13 + ty;
      txg[nt][r] = (tx >= 4); tyg[nt][r] = (ty >= 4);
      tvl[nt][r] = (t < S_);
    }

  if (maskR || maskC) {      // uniform branch: ~12% of blocks
    #pragma unroll
    for (int mt = 0; mt < 4; ++mt) {
      const int m = 16 * mt + l15;
      const int mc = m < S_ ? m : S_ - 1;
      const int px = mc / 7, py = mc - 7 * px;
      const bool pxg = (px >= 4), pyg = (py >= 4);
      #pragma unroll
      for (int nt = 0; nt < 4; ++nt)
        #pragma unroll
        for (int r = 0; r < 4; ++r) {
          if ((maskR && (pxg != txg[nt][r])) || (maskC && (pyg != tyg[nt][r])))
            st[nt][mt][r] = -INFINITY;
        }
    }
  }

  __syncthreads();   // barrier #1: posl ready; also fences ALL plane reads
                     // (QK frag loads) -> outb aliasing below is safe

  // scale + bias + exp -> pack P^T fragments (register-local; k-order matches vfr)
  const float scale = 0.17677669529663687f;   // 1/sqrt(32)
  short8 pvb[4][2];   // [mt][ks]; elem j = j2*4+r <-> t = 16(2ks+j2)+4g+r
  #pragma unroll
  for (int mt = 0; mt < 4; ++mt) {
    const int m = 16 * mt + l15;
    const int mc = m < S_ ? m : S_ - 1;
    const int px = mc / 7, py = mc - 7 * px;
    const int pofs = 84 - px * 13 - py;
    union { short8 s8; unsigned short h[8]; } pk[2];
    #pragma unroll
    for (int nt = 0; nt < 4; ++nt)
      #pragma unroll
      for (int r = 0; r < 4; ++r) {
        float s = st[nt][mt][r] * scale + posl[tix[nt][r] + pofs];
        float e = tvl[nt][r] ? __expf(s) : 0.f;
        pk[nt >> 1].h[(nt & 1) * 4 + r] = f2bf(e);
      }
    pvb[mt][0] = pk[0].s8;
    pvb[mt][1] = pk[1].s8;
  }

  // PV: O^T = V^T . P^T ; denominators via ones-operand MFMA
  f32x4 o_[2][4], d_[4];
  #pragma unroll
  for (int mt = 0; mt < 4; ++mt) {
    o_[0][mt] = (f32x4){0.f, 0.f, 0.f, 0.f};
    o_[1][mt] = (f32x4){0.f, 0.f, 0.f, 0.f};
    d_[mt]    = (f32x4){0.f, 0.f, 0.f, 0.f};
  }
  {
    union { short8 s8; unsigned short h[8]; } one;
    #pragma unroll
    for (int j = 0; j < 8; ++j) one.h[j] = 0x3F80;   // bf16 1.0
    #pragma unroll
    for (int ks = 0; ks < 2; ++ks) {
      #pragma unroll
      for (int mt = 0; mt < 4; ++mt) {
        o_[0][mt] = __builtin_amdgcn_mfma_f32_16x16x32_bf16(vfr[0][ks], pvb[mt][ks], o_[0][mt], 0, 0, 0);
        o_[1][mt] = __builtin_amdgcn_mfma_f32_16x16x32_bf16(vfr[1][ks], pvb[mt][ks], o_[1][mt], 0, 0, 0);
        d_[mt]    = __builtin_amdgcn_mfma_f32_16x16x32_bf16(one.s8,    pvb[mt][ks], d_[mt],    0, 0, 0);
      }
    }
  }
  // (no barrier here: outb's last readers were the QK frag loads, fenced by
  //  barrier #1; pack reads posl (>=32896), disjoint from outb bytes 0..25872.)

  // O^T tile: row e = 16et+4g+r, col m = 16mt+l15; d rows all identical
  float (*outb)[132] = (float (*)[132])smem;
  #pragma unroll
  for (int mt = 0; mt < 4; ++mt) {
    const int m = 16 * mt + l15;
    if (m < S_) {
      const float inv = 1.f / d_[mt][0];
      #pragma unroll
      for (int et = 0; et < 2; ++et)
        #pragma unroll
        for (int r = 0; r < 4; ++r)
          outb[m][(16 * et + 4 * g + r) * 4 + wv] = o_[et][mt][r] * inv;
    }
  }
  __syncthreads();   // all outb writes visible before cross-wave read-back

  // ---- coalesced output with un-roll(+3)
  for (int idx = tid; idx < S_ * 32; idx += 256) {
    const int pp = idx >> 5, c4 = idx & 31;
    const int ppx = pp / 7, ppy = pp % 7;
    const int fi = (wh * 7 + ppx + 3) % H_;
    const int fj = (ww * 7 + ppy + 3) % W_;
    float4 val = *(const float4*)&outb[pp][c4 * 4];
    ((float4*)(out + (((size_t)b * H_ + fi) * W_ + fj) * 128))[c4] = val;
  }
}

extern "C" void kernel_launch(void* const* d_in, const int* in_sizes, int n_in,
                              void* d_out, int out_size, void* d_ws, size_t ws_size,
                              hipStream_t stream) {
  const float* x   = (const float*)d_in[0];
  const float* v   = (const float*)d_in[1];
  const float* Wqk = (const float*)d_in[2];
  const float* bqk = (const float*)d_in[3];
  const float* pos = (const float*)d_in[4];
  float* out = (float*)d_out;
  unsigned short* Wb = (unsigned short*)d_ws;   // 65536 B (do NOT use ws beyond this)

  hipLaunchKernelGGL(wprep, dim3(32), dim3(256), 0, stream, Wqk, Wb);
  hipLaunchKernelGGL(swin_fused, dim3(B_ * WT * WT), dim3(256), 0, stream,
                     x, v, bqk, pos, Wb, out);
}

// Round 25
// 110.419 us; speedup vs baseline: 1.7764x; 1.7764x over previous
//
#include <hip/hip_runtime.h>
#include <hip/hip_bf16.h>
#include <math.h>

#define NH_ 4
#define S_  49
#define B_  16
#define H_  112
#define W_  112
#define WT  16

typedef __attribute__((ext_vector_type(8))) short short8;
typedef __attribute__((ext_vector_type(4))) float f32x4;

__device__ __forceinline__ unsigned short f2bf(float f) {
  union { __hip_bfloat16 h; unsigned short u; } c;
  c.h = __float2bfloat16(f);
  return c.u;
}
__device__ __forceinline__ short8 cvt8(float4 a, float4 b) {
  union { short8 s; unsigned short u[8]; } r;
  r.u[0] = f2bf(a.x); r.u[1] = f2bf(a.y); r.u[2] = f2bf(a.z); r.u[3] = f2bf(a.w);
  r.u[4] = f2bf(b.x); r.u[5] = f2bf(b.y); r.u[6] = f2bf(b.z); r.u[7] = f2bf(b.w);
  return r.s;
}

// ---- prep: Wqk f32 [256][128] -> bf16, HEAD-GROUPED row order:
//   Wb'[n'] = Wqk[orig], n' = h*64 + c, orig = 8*(c>>1) + 2h + (c&1).
//   (first 64 KB of ws ONLY — reads past d_ws+65536 proved unreliable r5-7)
__global__ void wprep(const float* __restrict__ Wqk, unsigned short* __restrict__ Wb) {
  int oi = (blockIdx.x * 256 + threadIdx.x) * 4;   // output element index
  int np = oi >> 7;          // n' = 0..255
  int k  = oi & 127;
  int h = np >> 6, c = np & 63;
  int orig = 8 * (c >> 1) + 2 * h + (c & 1);
  float4 w = *(const float4*)(Wqk + orig * 128 + k);
  ushort4 o; o.x = f2bf(w.x); o.y = f2bf(w.y); o.z = f2bf(w.z); o.w = f2bf(w.w);
  *(ushort4*)(Wb + oi) = o;
}

// LDS map (bytes) — r9 layout (plane CONTENTS identical to r19):
//   0     : qk planes, 8 x 4112 = 32896 (plane = head*2+s; [64 rows][32 e] bf16, 16B skew)
//           outb f32 [49][132] = 25872 aliases after barrier #1 (last plane reads = QK)
//   32896 : Vt_p bf16 4 x [32 e][72 slots] = 18432 (k-permuted pixel slots, p>=49 zeroed)
//   51328 : posl f32 [169] = 676      -> total 52004 -> 3 blocks/CU
#define PSTR   4112
#define SM_VT  32896
#define SM_POS 51328
#define SM_TOT 52004

__global__ __launch_bounds__(256, 3) void swin_fused(
    const float* __restrict__ x, const float* __restrict__ v,
    const float* __restrict__ bqk, const float* __restrict__ pos,
    const unsigned short* __restrict__ Wb, float* __restrict__ out)
{
  __shared__ __align__(16) char smem[SM_TOT];
  float* posl = (float*)(smem + SM_POS);

  const int tid  = threadIdx.x;
  const int lane = tid & 63;
  const int g    = lane >> 4, l15 = lane & 15;
  const int wv   = tid >> 6;
  const int blk  = blockIdx.x;
  const int ww   = blk % WT, wh = (blk / WT) % WT, b = blk / (WT * WT);

  if (tid < 169) posl[tid] = pos[tid];

  // ---- up-front loads: 4 biases (own head) + 8 v float4
  float bq[4];
  #pragma unroll
  for (int q = 0; q < 4; ++q)
    bq[q] = bqk[64 * q + 8 * (l15 >> 1) + 2 * wv + (l15 & 1)];

  float4 vS[8];
  #pragma unroll
  for (int it = 0; it < 2; ++it) {
    const int idx = tid + it * 256;          // 0..511
    const int e = idx & 31, p4 = idx >> 5;
    #pragma unroll
    for (int j = 0; j < 4; ++j) {
      const int p = p4 * 4 + j;
      float4 vv = {0.f, 0.f, 0.f, 0.f};
      if (p < S_) {
        const int px = p / 7, py = p % 7;
        const int gi = (wh * 7 + px + 4) % H_;
        const int gj = (ww * 7 + py + 4) % W_;
        vv = ((const float4*)(v + (((size_t)b * H_ + gi) * W_ + gj) * 128))[e];
      }
      vS[it * 4 + j] = vv;
    }
  }

  // ---- A-fragments for ALL 4 m-tiles (wave owns whole window for its head)
  short8 af[4][4];
  #pragma unroll
  for (int mt = 0; mt < 4; ++mt) {
    const int prow = 16 * mt + l15;
    const int pc = prow < S_ ? prow : S_ - 1;   // clamp; rows >=49 discarded later
    const int px = pc / 7, py = pc % 7;
    const int gi = (wh * 7 + px + 4) % H_;
    const int gj = (ww * 7 + py + 4) % W_;
    const float* xrow = x + (((size_t)b * H_ + gi) * W_ + gj) * 128;
    #pragma unroll
    for (int kk = 0; kk < 4; ++kk) {
      float4 a0 = *(const float4*)(xrow + kk * 32 + g * 8);
      float4 a1 = *(const float4*)(xrow + kk * 32 + g * 8 + 4);
      af[mt][kk] = cvt8(a0, a1);
    }
  }

  // ---- Vt_p build from staged v: pixel t stored at permuted k-slot.
  //   t = 16b1b0 + 4gg + rr -> k = 32b1 + 8gg + 4b0 + rr (bijective on 0..63)
  #pragma unroll
  for (int it = 0; it < 2; ++it) {
    const int idx = tid + it * 256;
    const int e = idx & 31, p4 = idx >> 5;
    const int kbase = 32 * (p4 >> 3) + 8 * (p4 & 3) + 4 * ((p4 >> 2) & 1);
    union { ushort4 v4; unsigned short u[4]; } hv[4];
    #pragma unroll
    for (int j = 0; j < 4; ++j) {
      float4 vv = vS[it * 4 + j];
      hv[0].u[j] = f2bf(vv.x); hv[1].u[j] = f2bf(vv.y);
      hv[2].u[j] = f2bf(vv.z); hv[3].u[j] = f2bf(vv.w);
    }
    #pragma unroll
    for (int h = 0; h < 4; ++h)
      *(ushort4*)(smem + SM_VT + h * 4608 + e * 144 + kbase * 2) = hv[h].v4;
  }

  // ---- projection, head-local: wave wv computes all 64 rows x its head's 64
  //      channels (Wb' rows wv*64 .. wv*64+63). Writes ONLY its own planes ->
  //      QK^T below needs no cross-wave barrier.
  {
    char* plane0 = smem + (wv * 2) * PSTR;
    #pragma unroll
    for (int q = 0; q < 4; ++q) {
      const int nb = (wv * 64 + q * 16 + l15) * 128;
      short8 bfr[4];
      #pragma unroll
      for (int kk = 0; kk < 4; ++kk)
        bfr[kk] = *(const short8*)(Wb + nb + kk * 32 + g * 8);
      const float bias = bq[q];
      char* plane = plane0 + (l15 & 1) * PSTR;             // s = l15&1
      const int eoff = (q * 8 + (l15 >> 1)) * 2;           // e = 8q + (l15>>1)
      #pragma unroll
      for (int mt = 0; mt < 4; ++mt) {
        f32x4 acc = {0.f, 0.f, 0.f, 0.f};
        #pragma unroll
        for (int kk = 0; kk < 4; ++kk)
          acc = __builtin_amdgcn_mfma_f32_16x16x32_bf16(af[mt][kk], bfr[kk], acc, 0, 0, 0);
        const int mbase = 16 * mt + 4 * g;
        #pragma unroll
        for (int r = 0; r < 4; ++r)
          *(unsigned short*)(plane + (mbase + r) * 64 + eoff) = f2bf(acc[r] + bias);
      }
    }
  }
  // (no barrier: planes of head wv are wave-private; lgkmcnt orders RAW below)

  // ---- attention: wave = head; SWAPPED QK^T -> lane-local P columns
  const bool maskR = (wh == WT - 1), maskC = (ww == WT - 1);
  const char* qpl = smem + (wv * 2 + 0) * PSTR;
  const char* kpl = smem + (wv * 2 + 1) * PSTR;
  short8 qf[4], kf[4];
  #pragma unroll
  for (int t4 = 0; t4 < 4; ++t4) {
    qf[t4] = *(const short8*)(qpl + (16 * t4 + l15) * 64 + g * 16);
    kf[t4] = *(const short8*)(kpl + (16 * t4 + l15) * 64 + g * 16);
  }

  // st[nt][mt]: D[row = t = 16nt+4g+r][col = m = 16mt+l15]
  f32x4 st[4][4];
  #pragma unroll
  for (int nt = 0; nt < 4; ++nt)
    #pragma unroll
    for (int mt = 0; mt < 4; ++mt) {
      f32x4 z = {0.f, 0.f, 0.f, 0.f};
      st[nt][mt] = __builtin_amdgcn_mfma_f32_16x16x32_bf16(kf[nt], qf[mt], z, 0, 0, 0);
    }

  // ---- t-geometry + shift masks BEFORE the barrier (lane-local, no posl/Vt dep)
  int tix[4][4]; bool txg[4][4], tyg[4][4], tvl[4][4];
  #pragma unroll
  for (int nt = 0; nt < 4; ++nt)
    #pragma unroll
    for (int r = 0; r < 4; ++r) {
      const int t = 16 * nt + 4 * g + r;
      const int tx = t / 7, ty = t - 7 * tx;
      tix[nt][r] = tx * 13 + ty;
      txg[nt][r] = (tx >= 4); tyg[nt][r] = (ty >= 4);
      tvl[nt][r] = (t < S_);
    }

  if (maskR || maskC) {      // uniform branch: ~12% of blocks
    #pragma unroll
    for (int mt = 0; mt < 4; ++mt) {
      const int m = 16 * mt + l15;
      const int mc = m < S_ ? m : S_ - 1;
      const int px = mc / 7, py = mc - 7 * px;
      const bool pxg = (px >= 4), pyg = (py >= 4);
      #pragma unroll
      for (int nt = 0; nt < 4; ++nt)
        #pragma unroll
        for (int r = 0; r < 4; ++r) {
          if ((maskR && (pxg != txg[nt][r])) || (maskC && (pyg != tyg[nt][r])))
            st[nt][mt][r] = -INFINITY;
        }
    }
  }

  __syncthreads();   // barrier #1: posl + Vt ready; also fences ALL plane reads
                     // (QK frag loads) -> outb aliasing below is safe

  // scale + bias + exp -> pack P^T fragments (register-local; k-order matches Vt_p)
  const float scale = 0.17677669529663687f;   // 1/sqrt(32)
  short8 pvb[4][2];   // [mt][ks]; elem j = j2*4+r <-> t = 16(2ks+j2)+4g+r
  #pragma unroll
  for (int mt = 0; mt < 4; ++mt) {
    const int m = 16 * mt + l15;
    const int mc = m < S_ ? m : S_ - 1;
    const int px = mc / 7, py = mc - 7 * px;
    const int pofs = 84 - px * 13 - py;
    union { short8 s8; unsigned short h[8]; } pk[2];
    #pragma unroll
    for (int nt = 0; nt < 4; ++nt)
      #pragma unroll
      for (int r = 0; r < 4; ++r) {
        float s = st[nt][mt][r] * scale + posl[tix[nt][r] + pofs];
        float e = tvl[nt][r] ? __expf(s) : 0.f;
        pk[nt >> 1].h[(nt & 1) * 4 + r] = f2bf(e);
      }
    pvb[mt][0] = pk[0].s8;
    pvb[mt][1] = pk[1].s8;
  }

  // PV: O^T = V^T . P^T ; denominators via ones-operand MFMA
  f32x4 o_[2][4], d_[4];
  #pragma unroll
  for (int mt = 0; mt < 4; ++mt) {
    o_[0][mt] = (f32x4){0.f, 0.f, 0.f, 0.f};
    o_[1][mt] = (f32x4){0.f, 0.f, 0.f, 0.f};
    d_[mt]    = (f32x4){0.f, 0.f, 0.f, 0.f};
  }
  {
    const char* Vb = smem + SM_VT + wv * 4608;
    union { short8 s8; unsigned short h[8]; } one;
    #pragma unroll
    for (int j = 0; j < 8; ++j) one.h[j] = 0x3F80;   // bf16 1.0
    #pragma unroll
    for (int ks = 0; ks < 2; ++ks) {
      short8 va[2];
      #pragma unroll
      for (int et = 0; et < 2; ++et)
        va[et] = *(const short8*)(Vb + (16 * et + l15) * 144 + ks * 64 + g * 16);
      #pragma unroll
      for (int mt = 0; mt < 4; ++mt) {
        o_[0][mt] = __builtin_amdgcn_mfma_f32_16x16x32_bf16(va[0], pvb[mt][ks], o_[0][mt], 0, 0, 0);
        o_[1][mt] = __builtin_amdgcn_mfma_f32_16x16x32_bf16(va[1], pvb[mt][ks], o_[1][mt], 0, 0, 0);
        d_[mt]    = __builtin_amdgcn_mfma_f32_16x16x32_bf16(one.s8, pvb[mt][ks], d_[mt], 0, 0, 0);
      }
    }
  }
  // (no barrier here: outb region's last readers were the QK frag loads, fenced
  //  by barrier #1; PV reads Vt (>=32896) and pack reads posl (>=51328), both
  //  disjoint from outb bytes 0..25872; per-wave outb columns are disjoint.)

  // O^T tile: row e = 16et+4g+r, col m = 16mt+l15; d rows all identical
  float (*outb)[132] = (float (*)[132])smem;
  #pragma unroll
  for (int mt = 0; mt < 4; ++mt) {
    const int m = 16 * mt + l15;
    if (m < S_) {
      const float inv = 1.f / d_[mt][0];
      #pragma unroll
      for (int et = 0; et < 2; ++et)
        #pragma unroll
        for (int r = 0; r < 4; ++r)
          outb[m][(16 * et + 4 * g + r) * 4 + wv] = o_[et][mt][r] * inv;
    }
  }
  __syncthreads();   // all outb writes visible before cross-wave read-back

  // ---- coalesced output with un-roll(+3)
  for (int idx = tid; idx < S_ * 32; idx += 256) {
    const int pp = idx >> 5, c4 = idx & 31;
    const int ppx = pp / 7, ppy = pp % 7;
    const int fi = (wh * 7 + ppx + 3) % H_;
    const int fj = (ww * 7 + ppy + 3) % W_;
    float4 val = *(const float4*)&outb[pp][c4 * 4];
    ((float4*)(out + (((size_t)b * H_ + fi) * W_ + fj) * 128))[c4] = val;
  }
}

extern "C" void kernel_launch(void* const* d_in, const int* in_sizes, int n_in,
                              void* d_out, int out_size, void* d_ws, size_t ws_size,
                              hipStream_t stream) {
  const float* x   = (const float*)d_in[0];
  const float* v   = (const float*)d_in[1];
  const float* Wqk = (const float*)d_in[2];
  const float* bqk = (const float*)d_in[3];
  const float* pos = (const float*)d_in[4];
  float* out = (float*)d_out;
  unsigned short* Wb = (unsigned short*)d_ws;   // 65536 B (do NOT use ws beyond this)

  hipLaunchKernelGGL(wprep, dim3(32), dim3(256), 0, stream, Wqk, Wb);
  hipLaunchKernelGGL(swin_fused, dim3(B_ * WT * WT), dim3(256), 0, stream,
                     x, v, bqk, pos, Wb, out);
}